// Round 4
// baseline (241.844 us; speedup 1.0000x reference)
//
#include <hip/hip_runtime.h>

static constexpr int B = 4;
static constexpr int N = 8192;
static constexpr int H = 8;
static constexpr int BH = B * H;   // 32
#define EPSF 1e-6f

typedef _Float16 f16;
typedef _Float16 f16x8 __attribute__((ext_vector_type(8)));
typedef float f32x4 __attribute__((ext_vector_type(4)));

__device__ __forceinline__ float featmap(float x) {
    return x > 0.0f ? (x + 1.0f) : __expf(x);   // elu(x)+1
}

// ---------------------------------------------------------------------------
// Pass 1: KV[bh][m][d] = sum_n V[n][m]*fK[n][d];  Ksum[bh][d] = sum_n fK[n][d]
// BARRIER-FREE, LDS-FREE. grid (BH, 8), block 256 = 4 autonomous waves.
// Wave w of block (bh,y) owns chunk = y*4+w (256 n-rows, 8 steps of 32).
// Fragments are loaded DIRECTLY from the natural [n][d] global layout:
//   A (V): row=l15 -> m, k=quad*8+j -> n ; B (K): col=l15 -> d, k=quad*8+j -> n
// Each (tile,j) load: 16 lanes read 64B contiguous (coalesced). f32 -> f16 cvt
// in registers. No __syncthreads => step s+1 loads stay in flight during
// step s cvt+MFMA (the old barrier drained vmcnt(0) every step -- the 52us
// invariant across 3 rounds of occupancy changes).
// ---------------------------------------------------------------------------
static constexpr int S1 = 32;            // partial slots per bh (ws layout as before)
static constexpr int CHUNK1 = N / S1;    // 256 rows per wave
static constexpr int NST1 = CHUNK1 / 32; // 8 steps

template<bool ATOMIC>
__global__ __launch_bounds__(256, 1) void kv_pass(
    const float* __restrict__ keys,
    const float* __restrict__ values,
    const float* __restrict__ mask,
    float* __restrict__ kv,     // ATOMIC: [BH][64][64] pre-zeroed; else [S1][BH][64][64]
    float* __restrict__ ksum)   // ATOMIC: [BH][64] pre-zeroed;     else [S1][BH][64]
{
    const int bh = blockIdx.x, b = bh >> 3, h = bh & 7;
    const int wave = threadIdx.x >> 6, lane = threadIdx.x & 63;
    const int quad = lane >> 4, l15 = lane & 15;
    const int chunk = blockIdx.y * 4 + wave;   // 0..31
    const int nb = chunk * CHUNK1;

    // element ((b*N+n)*H+h)*64 + d  ==  b*N*H*64 + h*64 + n*512 + d
    const float* kbase = keys   + (size_t)b * N * H * 64 + h * 64;
    const float* vbase = values + (size_t)b * N * H * 64 + h * 64;
    const float* mrow  = mask + (size_t)b * N;

    float ak[4][8], av[4][8], mk[8];

    auto load_step = [&](int n00) {
        #pragma unroll
        for (int j = 0; j < 8; ++j) {
            const int n = n00 + quad * 8 + j;
            const size_t ro = (size_t)n * 512;
            mk[j] = mrow[n];
            #pragma unroll
            for (int dt = 0; dt < 4; ++dt) ak[dt][j] = kbase[ro + dt * 16 + l15];
            #pragma unroll
            for (int mt = 0; mt < 4; ++mt) av[mt][j] = vbase[ro + mt * 16 + l15];
        }
    };
    load_step(nb);   // prologue prefetch

    f32x4 acc[4][4];
    #pragma unroll
    for (int i = 0; i < 4; ++i)
        #pragma unroll
        for (int jj = 0; jj < 4; ++jj) acc[i][jj] = (f32x4){0.f, 0.f, 0.f, 0.f};
    float ksacc[4] = {0.f, 0.f, 0.f, 0.f};

    for (int s = 0; s < NST1; ++s) {
        // convert current step's staging regs to MFMA fragments
        f16x8 af[4], bf[4];
        #pragma unroll
        for (int mt = 0; mt < 4; ++mt)
            #pragma unroll
            for (int j = 0; j < 8; ++j) af[mt][j] = (f16)av[mt][j];
        #pragma unroll
        for (int dt = 0; dt < 4; ++dt)
            #pragma unroll
            for (int j = 0; j < 8; ++j) {
                const float fk = featmap(ak[dt][j]) * mk[j];
                ksacc[dt] += fk;
                bf[dt][j] = (f16)fk;
            }
        // issue next step's loads (overwrite staging; in flight during MFMA)
        if (s + 1 < NST1) load_step(nb + (s + 1) * 32);
        // 16 MFMA: D[m-tile][d-tile]
        #pragma unroll
        for (int mt = 0; mt < 4; ++mt)
            #pragma unroll
            for (int dt = 0; dt < 4; ++dt)
                acc[mt][dt] = __builtin_amdgcn_mfma_f32_16x16x32_f16(af[mt], bf[dt], acc[mt][dt], 0, 0, 0);
    }

    // epilogue: D row = m = mt*16 + quad*4 + reg, col = d = dt*16 + l15
    float* kvb = ATOMIC ? (kv + (size_t)bh * 4096)
                        : (kv + ((size_t)chunk * BH + bh) * 4096);
    #pragma unroll
    for (int mt = 0; mt < 4; ++mt)
        #pragma unroll
        for (int dt = 0; dt < 4; ++dt)
            #pragma unroll
            for (int reg = 0; reg < 4; ++reg) {
                const int idx = (mt * 16 + quad * 4 + reg) * 64 + dt * 16 + l15;
                if (ATOMIC) atomicAdd(kvb + idx, acc[mt][dt][reg]);
                else        kvb[idx] = acc[mt][dt][reg];
            }
    // Ksum: lane holds d=dt*16+l15 partial over its n-subset; reduce over quads
    #pragma unroll
    for (int dt = 0; dt < 4; ++dt) {
        float v = ksacc[dt];
        v += __shfl_xor(v, 16);
        v += __shfl_xor(v, 32);
        if (quad == 0) {
            if (ATOMIC) atomicAdd(ksum + bh * 64 + dt * 16 + l15, v);
            else        ksum[((size_t)chunk * (BH * 64)) + bh * 64 + dt * 16 + l15] = v;
        }
    }
}

// ---------------------------------------------------------------------------
// Sum the S1 partial tiles: kv[idx] = sum_s pkv[s][idx], ksum likewise.
// ---------------------------------------------------------------------------
__global__ __launch_bounds__(256) void reduce_pass(
    const float* __restrict__ pkv, const float* __restrict__ pks,
    float* __restrict__ kv, float* __restrict__ ksum)
{
    const int idx = blockIdx.x * 256 + threadIdx.x;
    if (idx < BH * 4096) {
        float s = 0.f;
        #pragma unroll 8
        for (int j = 0; j < S1; ++j) s += pkv[(size_t)j * (BH * 4096) + idx];
        kv[idx] = s;
    } else if (idx < BH * 4096 + BH * 64) {
        const int k = idx - BH * 4096;
        float s = 0.f;
        #pragma unroll 8
        for (int j = 0; j < S1; ++j) s += pks[(size_t)j * (BH * 64) + k];
        ksum[k] = s;
    }
}

// ---------------------------------------------------------------------------
// Pass 2: out[n][m] = (sum_d fQ[n][d]*KV[m][d]) / (sum_d fQ[n][d]*Ksum[d]+eps)
// BARRIER-FREE, LDS-FREE. grid (BH, 16), block 256 = 4 autonomous waves.
// Wave owns 128 n-rows = 8 tiles of 16. B-frags (KV + Ksum z-column) loaded
// once per wave directly from global (2xfloat4/lane, L2-resident); per tile
// the A-frag (fQ) is 4xfloat4/lane, prefetched one tile ahead.
// ---------------------------------------------------------------------------
static constexpr int S2 = 16;
static constexpr int WCHUNK2 = 128;           // rows per wave
static constexpr int TILES2 = WCHUNK2 / 16;   // 8

__global__ __launch_bounds__(256, 1) void out_pass(
    const float* __restrict__ queries,
    const float* __restrict__ kv,
    const float* __restrict__ ksum,
    float* __restrict__ out)
{
    const int bh = blockIdx.x, b = bh >> 3, h = bh & 7;
    const int wave = threadIdx.x >> 6, lane = threadIdx.x & 63;
    const int quad = lane >> 4, l15 = lane & 15;
    const int nb = (blockIdx.y * 4 + wave) * WCHUNK2;

    // B-frags: B[col=m=l15][k=d=ks*32+quad*8+j] from KV[m][d] (row-major)
    f16x8 bfr[4][2];
    #pragma unroll
    for (int mt = 0; mt < 4; ++mt)
        #pragma unroll
        for (int ks = 0; ks < 2; ++ks) {
            const float* p = kv + (size_t)bh * 4096 + (mt * 16 + l15) * 64 + ks * 32 + quad * 8;
            const float4 a0 = *(const float4*)p;
            const float4 a1 = *(const float4*)(p + 4);
            f16x8 f;
            f[0] = (f16)a0.x; f[1] = (f16)a0.y; f[2] = (f16)a0.z; f[3] = (f16)a0.w;
            f[4] = (f16)a1.x; f[5] = (f16)a1.y; f[6] = (f16)a1.z; f[7] = (f16)a1.w;
            bfr[mt][ks] = f;
        }
    // z-frag: Ksum in col 0 only
    f16x8 bz[2];
    #pragma unroll
    for (int ks = 0; ks < 2; ++ks) {
        const float* z = ksum + bh * 64 + ks * 32 + quad * 8;
        const float4 z0 = *(const float4*)z;
        const float4 z1 = *(const float4*)(z + 4);
        f16x8 f;
        f[0] = (f16)z0.x; f[1] = (f16)z0.y; f[2] = (f16)z0.z; f[3] = (f16)z0.w;
        f[4] = (f16)z1.x; f[5] = (f16)z1.y; f[6] = (f16)z1.z; f[7] = (f16)z1.w;
        if (l15 != 0) {
            #pragma unroll
            for (int j = 0; j < 8; ++j) f[j] = (f16)0.f;
        }
        bz[ks] = f;
    }

    const float* qbase = queries + (size_t)b * N * H * 64 + h * 64;
    float* obase = out + (size_t)b * N * H * 64 + h * 64;

    float4 qs[2][2];
    auto loadq = [&](int t) {
        const int n = nb + t * 16 + l15;    // A row
        const float* p = qbase + (size_t)n * 512;
        #pragma unroll
        for (int ks = 0; ks < 2; ++ks) {
            qs[ks][0] = *(const float4*)(p + ks * 32 + quad * 8);
            qs[ks][1] = *(const float4*)(p + ks * 32 + quad * 8 + 4);
        }
    };
    loadq(0);

    for (int t = 0; t < TILES2; ++t) {
        // A-frags: featmap + cvt
        f16x8 afr[2];
        #pragma unroll
        for (int ks = 0; ks < 2; ++ks) {
            f16x8 f;
            f[0] = (f16)featmap(qs[ks][0].x); f[1] = (f16)featmap(qs[ks][0].y);
            f[2] = (f16)featmap(qs[ks][0].z); f[3] = (f16)featmap(qs[ks][0].w);
            f[4] = (f16)featmap(qs[ks][1].x); f[5] = (f16)featmap(qs[ks][1].y);
            f[6] = (f16)featmap(qs[ks][1].z); f[7] = (f16)featmap(qs[ks][1].w);
            afr[ks] = f;
        }
        if (t + 1 < TILES2) loadq(t + 1);   // prefetch next tile

        f32x4 acc[4];
        #pragma unroll
        for (int i = 0; i < 4; ++i) acc[i] = (f32x4){0.f, 0.f, 0.f, 0.f};
        f32x4 az = (f32x4){0.f, 0.f, 0.f, 0.f};

        #pragma unroll
        for (int ks = 0; ks < 2; ++ks) {
            #pragma unroll
            for (int mt = 0; mt < 4; ++mt)
                acc[mt] = __builtin_amdgcn_mfma_f32_16x16x32_f16(afr[ks], bfr[mt][ks], acc[mt], 0, 0, 0);
            az = __builtin_amdgcn_mfma_f32_16x16x32_f16(afr[ks], bz[ks], az, 0, 0, 0);
        }

        // den in col 0 (l15==0) of az; broadcast within quad
        #pragma unroll
        for (int reg = 0; reg < 4; ++reg) {
            const float den = __shfl(az[reg], lane & 48);
            const float zin = 1.0f / (den + EPSF);
            const int nr = nb + t * 16 + quad * 4 + reg;   // D row
            float* op = obase + (size_t)nr * 512 + l15;
            #pragma unroll
            for (int mt = 0; mt < 4; ++mt)
                op[mt * 16] = acc[mt][reg] * zin;
        }
    }
}

extern "C" void kernel_launch(void* const* d_in, const int* in_sizes, int n_in,
                              void* d_out, int out_size, void* d_ws, size_t ws_size,
                              hipStream_t stream)
{
    const float* q    = (const float*)d_in[0];
    const float* k    = (const float*)d_in[1];
    const float* v    = (const float*)d_in[2];
    const float* mask = (const float*)d_in[3];
    float* out = (float*)d_out;

    const size_t PKV = (size_t)S1 * BH * 4096;
    const size_t PKS = (size_t)S1 * BH * 64;
    const size_t FIN = (size_t)BH * 4096 + BH * 64;
    const size_t need = (PKV + PKS + FIN) * sizeof(float);

    if (ws_size >= need) {
        float* pkv = (float*)d_ws;
        float* pks = pkv + PKV;
        float* kvf = pks + PKS;
        float* ksf = kvf + (size_t)BH * 4096;
        kv_pass<false><<<dim3(BH, S1 / 4), 256, 0, stream>>>(k, v, mask, pkv, pks);
        const int redElems = BH * 4096 + BH * 64;
        reduce_pass<<<dim3((redElems + 255) / 256), 256, 0, stream>>>(pkv, pks, kvf, ksf);
        out_pass<<<dim3(BH, S2), 256, 0, stream>>>(q, kvf, ksf, out);
    } else {
        float* kvf = (float*)d_ws;
        float* ksf = kvf + (size_t)BH * 4096;
        hipMemsetAsync(d_ws, 0, FIN * sizeof(float), stream);
        kv_pass<true><<<dim3(BH, S1 / 4), 256, 0, stream>>>(k, v, mask, kvf, ksf);
        out_pass<<<dim3(BH, S2), 256, 0, stream>>>(q, kvf, ksf, out);
    }
}